// Round 12
// baseline (167.803 us; speedup 1.0000x reference)
//
#include <hip/hip_runtime.h>

typedef unsigned short u16;
typedef unsigned int u32;
typedef __attribute__((ext_vector_type(8))) short bf16x8;
typedef __attribute__((ext_vector_type(4))) float f32x4;
typedef __attribute__((ext_vector_type(16))) float f32x16;
typedef __attribute__((ext_vector_type(4))) unsigned short u16x4;
typedef __attribute__((ext_vector_type(4))) unsigned int u32x4;

#define NSPLIT 8

__device__ __forceinline__ u16 f2b(float f) {
  u32 u = __builtin_bit_cast(u32, f);
  u32 r = (u + 0x7FFFu + ((u >> 16) & 1u)) >> 16;  // RNE
  return (u16)r;
}

__device__ __forceinline__ f32x4 mfma16(bf16x8 a, bf16x8 b, f32x4 c) {
  return __builtin_amdgcn_mfma_f32_16x16x32_bf16(a, b, c, 0, 0, 0);
}
__device__ __forceinline__ f32x16 mfma32(bf16x8 a, bf16x8 b, f32x16 c) {
  return __builtin_amdgcn_mfma_f32_32x32x16_bf16(a, b, c, 0, 0, 0);
}
__device__ __forceinline__ u32 cvtpk(float lo, float hi) {
  u32 r;
  asm("v_cvt_pk_bf16_f32 %0, %1, %2" : "=v"(r) : "v"(lo), "v"(hi));
  return r;
}
__device__ __forceinline__ void pl32swap(u32& a, u32& b) {
  asm("v_permlane32_swap_b32 %0, %1" : "+v"(a), "+v"(b));
}

// ---------------- kernel 0: fused convert (fp32->bf16 frag-major) + Wvo ----
__global__ __launch_bounds__(256) void prep_kernel(
    const float* __restrict__ x, const float* __restrict__ wq,
    const float* __restrict__ wk, const float* __restrict__ Wo,
    const float* __restrict__ Wv,
    u16* __restrict__ xf, u16* __restrict__ wqf, u16* __restrict__ wkf,
    u16* __restrict__ wvof) {
  if (blockIdx.x < 1280) {
    int i = blockIdx.x * 256 + threadIdx.x;   // 327680 vec8 units
    const float* src; u16* dst; int off; float scale = 1.0f;
    if (i < 262144)      { src = x;  dst = xf;  off = i; }
    else if (i < 294912) { src = wq; dst = wqf; off = i - 262144; scale = 0.18033688011112042f; }
    else                 { src = wk; dst = wkf; off = i - 294912; }
    int row = off >> 6;
    int c = (off & 63) * 8;
    int blk = row >> 4, lr = row & 15, kk = c >> 5, lg = (c >> 3) & 3;
    size_t fidx = ((((size_t)blk * 16 + kk) * 4 + lg) * 16 + lr) * 8;
    const float4* s4 = (const float4*)src;
    float4 a = s4[off * 2], b = s4[off * 2 + 1];
    u16x4 r0, r1;
    r0.x = f2b(a.x * scale); r0.y = f2b(a.y * scale);
    r0.z = f2b(a.z * scale); r0.w = f2b(a.w * scale);
    r1.x = f2b(b.x * scale); r1.y = f2b(b.y * scale);
    r1.z = f2b(b.z * scale); r1.w = f2b(b.w * scale);
    *(u16x4*)(dst + fidx) = r0;
    *(u16x4*)(dst + fidx + 4) = r1;
  } else {
    int t = (blockIdx.x - 1280) * 256 + threadIdx.x;   // 262144
    int h = t >> 15, i = (t >> 9) & 63, j = t & 511;
    const float* worow = Wo + (size_t)i * 512 + h * 64;
    const float* wvcol = Wv + (size_t)(h * 64) * 512 + j;
    float s = 0.0f;
#pragma unroll 8
    for (int d = 0; d < 64; ++d) s += worow[d] * wvcol[(size_t)d * 512];
    int row = h * 64 + i;
    int cb = row >> 4, lr = row & 15, kk = j >> 5, lg = (j >> 3) & 3, jj = j & 7;
    wvof[((((size_t)cb * 16 + kk) * 4 + lg) * 16 + lr) * 8 + jj] = f2b(s);
  }
}

// LDS byte offset with XOR swizzle: bank-spread for both write and read.
__device__ __forceinline__ int swz(int row, int colu16) {
  return row * 256 + (((colu16) * 2) ^ ((row & 15) << 4));
}

// ---------------- kernel 1: QKV projection, 64x128 tiles (768 blocks) ------
// grid (64, 12): rows [bx*64,+64); mode = by>>2, col-group cg = by&3.
// 3 blocks/CU exactly (no tail imbalance). MFMA -> swizzled LDS -> barrier
// -> coalesced dwordx4 global stores in attention-fragment order.
__global__ __launch_bounds__(256) void qkv_kernel(
    const u16* __restrict__ xf, const u16* __restrict__ wqf,
    const u16* __restrict__ wkf, const u16* __restrict__ wvof,
    u16* __restrict__ Qf, u16* __restrict__ Kf, u16* __restrict__ Vf) {
  __shared__ __align__(16) char tile[64 * 256];   // 64 rows x 128 u16
  int wave = threadIdx.x >> 6, lane = threadIdx.x & 63;
  int lr = lane & 15, lg = lane >> 4;
  int mode = blockIdx.y >> 2, cg = blockIdx.y & 3;
  const u16* W = (mode == 0) ? wqf : (mode == 1) ? wkf : wvof;
  f32x4 acc[8] = {};
  const u16* aB0 = xf + (size_t)(blockIdx.x * 4 + wave) * 8192 + lg * 128 + lr * 8;
  const u16* bB0 = W + (size_t)(cg * 8) * 8192 + lg * 128 + lr * 8;
#pragma unroll 4
  for (int kk = 0; kk < 16; ++kk) {
    bf16x8 aF = *(const bf16x8*)(aB0 + kk * 512);
#pragma unroll
    for (int ni = 0; ni < 8; ++ni) {
      bf16x8 bF = *(const bf16x8*)(bB0 + (size_t)ni * 8192 + kk * 512);
      acc[ni] = mfma16(aF, bF, acc[ni]);
    }
  }
  // scatter into LDS (swizzled; conflicts <=2-way)
#pragma unroll
  for (int ni = 0; ni < 8; ++ni)
#pragma unroll
    for (int r = 0; r < 4; ++r) {
      int row = wave * 16 + lg * 4 + r;
      int col = ni * 16 + lr;
      *(u16*)(tile + swz(row, col)) = f2b(acc[ni][r]);
    }
  __syncthreads();
  u16* dstBase = (mode == 0) ? Qf : (mode == 1) ? Kf : Vf;
  if (mode < 2) {
    // 16 runs: (hh, kbl, s) x lanes (hi2, l31); dwordx4 loads + stores
#pragma unroll
    for (int it = 0; it < 4; ++it) {
      int gid = wave * 4 + it;                  // 0..15
      int hh = gid >> 3, kbl = (gid >> 2) & 1, s = gid & 3;
      int hi2 = lane >> 5, l31 = lane & 31;
      int lrow = kbl * 32 + l31;
      int col = hh * 64 + s * 16 + hi2 * 8;
      u32x4 v = *(const u32x4*)(tile + swz(lrow, col));
      int h = cg * 2 + hh, kb = blockIdx.x * 2 + kbl;
      u16* dst = dstBase + (size_t)h * 262144 +
                 (((size_t)(kb * 4 + s) * 2 + hi2) * 32 + l31) * 8;
      *(u32x4*)dst = v;
    }
  } else {
    // 16 runs: (hh, ks, hi2v) x lanes d=0..63; gather 8 rows -> dwordx4
#pragma unroll
    for (int it = 0; it < 4; ++it) {
      int gid = wave * 4 + it;                  // 0..15
      int hh = gid >> 3, ks = (gid >> 1) & 3, hi2v = gid & 1;
      int d = lane;
      int r0 = ks * 16 + hi2v * 8;
      int col = hh * 64 + d;
      u32 wd[4];
#pragma unroll
      for (int jp = 0; jp < 4; ++jp) {
        u32 lo = *(const u16*)(tile + swz(r0 + 2 * jp, col));
        u32 hi = *(const u16*)(tile + swz(r0 + 2 * jp + 1, col));
        wd[jp] = lo | (hi << 16);
      }
      int h = cg * 2 + hh, kt = blockIdx.x;
      u16* dst = dstBase + (size_t)h * 262144 +
                 (((size_t)(kt * 4 + ks) * 2 + hi2v) * 64 + d) * 8;
      u32x4 v = {wd[0], wd[1], wd[2], wd[3]};
      *(u32x4*)dst = v;
    }
  }
}

// ---------------- kernel 2: flash attention, swapped-QK^T 32x32 ------------
// 2048 blocks (NSPLIT=8), 4 waves, NO LDS/barriers. 32-key subtiles, single
// K buffer with prefetch-into-same-regs, running pointers w/ imm offsets,
// setprio around MFMA clusters. Low VGPR -> 5 waves/SIMD.
__global__ __launch_bounds__(256) void attn_kernel(
    const u16* __restrict__ Qf, const u16* __restrict__ Kf,
    const u16* __restrict__ Vf, float* __restrict__ Pacc,
    float* __restrict__ Pl) {
  int bid = blockIdx.x;
  int h = bid & 7, idx = bid >> 3;
  int c = idx & 7, qb = idx >> 3;            // c: 512-key chunk, qb: 128 rows
  int warp = threadIdx.x >> 6, lane = threadIdx.x & 63;
  int l31 = lane & 31, hi = lane >> 5;
  int q = qb * 128 + warp * 32 + l31;
  const u16* Qh = Qf + (size_t)h * 262144;

  int qb32 = qb * 4 + warp;
  bf16x8 qf[4];
#pragma unroll
  for (int s = 0; s < 4; ++s)
    qf[s] = *(const bf16x8*)(Qh + ((size_t)(qb32 * 4 + s) * 2 + hi) * 256 + l31 * 8);

  // running pointers: advance 2048 elements (one 32-key group) per iter
  const u16* kptr = Kf + (size_t)h * 262144 + (size_t)c * 32768 + hi * 256 + l31 * 8;
  const u16* vptr = Vf + (size_t)h * 262144 + (size_t)c * 32768 + hi * 512 + l31 * 8;

  bf16x8 kq[4];
#pragma unroll
  for (int s = 0; s < 4; ++s)
    kq[s] = *(const bf16x8*)(kptr + s * 512);

  f32x16 o0 = {}, o1 = {};
  float l = 0.0f;

  for (int kk = 0; kk < 16; ++kk) {
    // ---- S^T = K_sub . Q^T (K in regs), 4-chain ----
    __builtin_amdgcn_s_setprio(1);
    f32x16 s = {};
#pragma unroll
    for (int si = 0; si < 4; ++si) s = mfma32(kq[si], qf[si], s);
    __builtin_amdgcn_s_setprio(0);
    // ---- prefetch next K group into same regs (WAR-safe) ----
    kptr += 2048;
#pragma unroll
    for (int si = 0; si < 4; ++si)
      kq[si] = *(const bf16x8*)(kptr + si * 512);
    // ---- V loads for this group (hidden under exp/pack) ----
    bf16x8 vf0 = *(const bf16x8*)(vptr);
    bf16x8 vf1 = *(const bf16x8*)(vptr + 256);
    bf16x8 vf2 = *(const bf16x8*)(vptr + 1024);
    bf16x8 vf3 = *(const bf16x8*)(vptr + 1280);
    vptr += 2048;
    // ---- P = exp2(S) directly (scores bounded), tree-sum into l ----
#pragma unroll
    for (int r = 0; r < 16; ++r) s[r] = __builtin_amdgcn_exp2f(s[r]);
    float u4[8];
#pragma unroll
    for (int i = 0; i < 8; ++i) u4[i] = s[i] + s[i + 8];
    l += ((u4[0] + u4[1]) + (u4[2] + u4[3])) + ((u4[4] + u4[5]) + (u4[6] + u4[7]));
    // ---- pack P -> bf16 words; permlane builds PV B-fragments ----
    u32 w0 = cvtpk(s[0], s[1]), w1 = cvtpk(s[2], s[3]);
    u32 w2 = cvtpk(s[4], s[5]), w3 = cvtpk(s[6], s[7]);
    u32 w4 = cvtpk(s[8], s[9]), w5 = cvtpk(s[10], s[11]);
    u32 w6 = cvtpk(s[12], s[13]), w7 = cvtpk(s[14], s[15]);
    pl32swap(w0, w2); pl32swap(w1, w3);
    pl32swap(w4, w6); pl32swap(w5, w7);
    // ---- PV: O^T += VW^T . P^T ----
    __builtin_amdgcn_s_setprio(1);
    u32x4 pwa = {w0, w1, w2, w3};
    bf16x8 pb0 = __builtin_bit_cast(bf16x8, pwa);
    o0 = mfma32(vf0, pb0, o0);
    o1 = mfma32(vf1, pb0, o1);
    u32x4 pwb = {w4, w5, w6, w7};
    bf16x8 pb1 = __builtin_bit_cast(bf16x8, pwb);
    o0 = mfma32(vf2, pb1, o0);
    o1 = mfma32(vf3, pb1, o1);
    __builtin_amdgcn_s_setprio(0);
  }
  l += __shfl_xor(l, 32);
  float* base = Pacc + ((size_t)(c * 8 + h) * 4096 + q) * 64;
#pragma unroll
  for (int g = 0; g < 4; ++g) {
    f32x4 v0 = {o0[4*g], o0[4*g+1], o0[4*g+2], o0[4*g+3]};
    f32x4 v1 = {o1[4*g], o1[4*g+1], o1[4*g+2], o1[4*g+3]};
    *(f32x4*)(base + 8 * g + 4 * hi) = v0;
    *(f32x4*)(base + 32 + 8 * g + 4 * hi) = v1;
  }
  if (!hi) Pl[(size_t)(c * 8 + h) * 4096 + q] = l;
}

// ---------------- kernel 2b: combine = Sum_h [Sum_c acc / Sum_c l] + bias --
__global__ __launch_bounds__(256) void combine_kernel(
    const float* __restrict__ Pacc, const float* __restrict__ Pl,
    const float* __restrict__ bo, float* __restrict__ out) {
  int t = blockIdx.x * 256 + threadIdx.x;   // 65536
  int n = t >> 4, dp = (t & 15) * 4;
  f32x4 acc = {0, 0, 0, 0};
#pragma unroll
  for (int h = 0; h < 8; ++h) {
    float lt = 0.0f;
#pragma unroll
    for (int cc = 0; cc < NSPLIT; ++cc)
      lt += Pl[(size_t)(cc * 8 + h) * 4096 + n];
    float inv = 1.0f / lt;
    f32x4 oh = {0, 0, 0, 0};
#pragma unroll
    for (int cc = 0; cc < NSPLIT; ++cc) {
      f32x4 a = *(const f32x4*)(Pacc + (size_t)(cc * 8 + h) * 262144 + (size_t)n * 64 + dp);
      oh.x += a.x; oh.y += a.y; oh.z += a.z; oh.w += a.w;
    }
    acc.x += oh.x * inv; acc.y += oh.y * inv;
    acc.z += oh.z * inv; acc.w += oh.w * inv;
  }
  f32x4 b4 = *(const f32x4*)(bo + dp);
  acc.x += b4.x; acc.y += b4.y; acc.z += b4.z; acc.w += b4.w;
  *(f32x4*)(out + (size_t)n * 64 + dp) = acc;
}

extern "C" void kernel_launch(void* const* d_in, const int* in_sizes, int n_in,
                              void* d_out, int out_size, void* d_ws, size_t ws_size,
                              hipStream_t stream) {
  const float* x  = (const float*)d_in[0];
  const float* Wq = (const float*)d_in[1];
  const float* Wk = (const float*)d_in[2];
  const float* Wv = (const float*)d_in[3];
  const float* Wo = (const float*)d_in[4];
  const float* bo = (const float*)d_in[5];
  float* out = (float*)d_out;

  u16* xf   = (u16*)d_ws;            // 4096x512 fragment-major
  u16* wqf  = xf + 2097152;          // 512x512 fragment-major
  u16* wkf  = wqf + 262144;
  u16* wvof = wkf + 262144;          // (Wo_h Wv_h) fragment-major
  u16* Qf   = wvof + 262144;         // 8 heads x 262144
  u16* Kf   = Qf + 2097152;
  u16* Vf   = Kf + 2097152;          // VW fragments
  float* Pacc = (float*)(Vf + 2097152);           // NSPLIT*8*4096*64 fp32
  float* Pl   = Pacc + (size_t)NSPLIT * 8 * 4096 * 64;  // NSPLIT*8*4096 fp32
  (void)in_sizes; (void)n_in; (void)out_size; (void)ws_size;

  prep_kernel<<<2304, 256, 0, stream>>>(x, Wq, Wk, Wo, Wv, xf, wqf, wkf, wvof);
  qkv_kernel<<<dim3(64, 12), 256, 0, stream>>>(xf, wqf, wkf, wvof, Qf, Kf, Vf);
  attn_kernel<<<2048, 256, 0, stream>>>(Qf, Kf, Vf, Pacc, Pl);
  combine_kernel<<<256, 256, 0, stream>>>(Pacc, Pl, bo, out);
}